// Round 3
// baseline (2879.654 us; speedup 1.0000x reference)
//
#include <hip/hip_runtime.h>

#define DV 1024
#define TT 4096
#define BB 4
#define FF 4096
#define MM (BB*TT)   // 16384 rows

typedef __attribute__((ext_vector_type(8))) short bf16x8;
typedef __attribute__((ext_vector_type(4))) float f32x4;
typedef __attribute__((ext_vector_type(8))) unsigned short u16x8;
typedef __attribute__((ext_vector_type(4))) unsigned short u16x4;

__device__ __forceinline__ float bf2f(unsigned short h) {
    union { unsigned int u; float f; } c; c.u = ((unsigned int)h) << 16; return c.f;
}
__device__ __forceinline__ unsigned short f2bf(float f) {
    union { float f; unsigned int u; } c; c.f = f;
    unsigned int r = c.u + 0x7fffu + ((c.u >> 16) & 1u);
    return (unsigned short)(r >> 16);
}

// diag: if workspace too small, expose ws_size via absmax
__global__ void diag_kernel(float* out, float v) { out[0] = v; }

// ---------------- weight cast+transpose: f32 [K][N] -> bf16 [N][K] ----------------
__global__ __launch_bounds__(256) void transpose_cast(
    const float* __restrict__ src, unsigned short* __restrict__ dst, int K, int N)
{
    __shared__ float t[32][33];
    int n0 = blockIdx.x * 32, k0 = blockIdx.y * 32;
    int tx = threadIdx.x, ty = threadIdx.y;  // block (32,8)
    #pragma unroll
    for (int i = 0; i < 4; ++i)
        t[ty*4+i][tx] = src[(size_t)(k0 + ty*4 + i) * N + n0 + tx];
    __syncthreads();
    #pragma unroll
    for (int i = 0; i < 4; ++i)
        dst[(size_t)(n0 + ty*4 + i) * K + k0 + tx] = f2bf(t[tx][ty*4+i]);
}

// ---------------- LayerNorm: (f32|bf16) [rows][1024] -> bf16 ----------------
template<bool BF16IN>
__global__ __launch_bounds__(256) void ln_kernel(
    const void* __restrict__ xin, const float* __restrict__ w, const float* __restrict__ b,
    unsigned short* __restrict__ out)
{
    int row = blockIdx.x;
    int t = threadIdx.x;
    float v0, v1, v2, v3;
    if (BF16IN) {
        u16x4 h = *(const u16x4*)((const unsigned short*)xin + (size_t)row * DV + t * 4);
        v0 = bf2f(h[0]); v1 = bf2f(h[1]); v2 = bf2f(h[2]); v3 = bf2f(h[3]);
    } else {
        float4 v = ((const float4*)((const float*)xin + (size_t)row * DV))[t];
        v0 = v.x; v1 = v.y; v2 = v.z; v3 = v.w;
    }
    float s = v0 + v1 + v2 + v3;
    float q = v0*v0 + v1*v1 + v2*v2 + v3*v3;
    #pragma unroll
    for (int off = 32; off >= 1; off >>= 1) {
        s += __shfl_down(s, off);
        q += __shfl_down(q, off);
    }
    __shared__ float ss[4], qq[4];
    if ((t & 63) == 0) { ss[t >> 6] = s; qq[t >> 6] = q; }
    __syncthreads();
    s = ss[0] + ss[1] + ss[2] + ss[3];
    q = qq[0] + qq[1] + qq[2] + qq[3];
    float mu = s * (1.f/DV);
    float var = q * (1.f/DV) - mu*mu;
    float rs = rsqrtf(var + 1e-5f);
    int d = t * 4;
    u16x4 o;
    o[0] = f2bf((v0 - mu)*rs*w[d+0] + b[d+0]);
    o[1] = f2bf((v1 - mu)*rs*w[d+1] + b[d+1]);
    o[2] = f2bf((v2 - mu)*rs*w[d+2] + b[d+2]);
    o[3] = f2bf((v3 - mu)*rs*w[d+3] + b[d+3]);
    *(u16x4*)(out + (size_t)row*DV + d) = o;
}

// ---------------- time-shift mix: out = xn*c + shift(xn)*(1-c), 2 or 3 outputs ----------------
__global__ __launch_bounds__(256) void mix_kernel(
    const unsigned short* __restrict__ xn,
    const float* __restrict__ ck, const float* __restrict__ cv, const float* __restrict__ cr,
    unsigned short* __restrict__ ok, unsigned short* __restrict__ ov, unsigned short* __restrict__ orr)
{
    int gid = blockIdx.x * 256 + threadIdx.x;   // MM*DV/8 total
    int row = gid >> 7;
    int d0 = (gid & 127) << 3;
    size_t base = (size_t)row * DV + d0;
    u16x8 cur = *(const u16x8*)(xn + base);
    bool hp = (row & (TT - 1)) != 0;
    u16x8 prev = (u16x8)0;
    if (hp) prev = *(const u16x8*)(xn + base - DV);
    u16x8 rk, rv, rr2;
    #pragma unroll
    for (int e = 0; e < 8; ++e) {
        float xc = bf2f(cur[e]);
        float xp = hp ? bf2f(prev[e]) : 0.f;
        float a = ck[d0+e]; rk[e] = f2bf(xc*a + xp*(1.f-a));
        float bb = cv[d0+e]; rv[e] = f2bf(xc*bb + xp*(1.f-bb));
        if (orr) { float c = cr[d0+e]; rr2[e] = f2bf(xc*c + xp*(1.f-c)); }
    }
    *(u16x8*)(ok + base) = rk;
    *(u16x8*)(ov + base) = rv;
    if (orr) *(u16x8*)(orr + base) = rr2;
}

// ---------------- WKV serial scan + sigmoid(r) gate, writes bf16 a = wkv*sr ----------------
__global__ __launch_bounds__(256) void wkv_kernel(
    const unsigned short* __restrict__ k, const unsigned short* __restrict__ v,
    const unsigned short* __restrict__ r,
    const float* __restrict__ time_decay, const float* __restrict__ time_first,
    unsigned short* __restrict__ aout)
{
    int tid = blockIdx.x * 256 + threadIdx.x;   // 0..4095
    int b = tid >> 10, d = tid & (DV - 1);
    float w = __expf(time_decay[d]);
    float u = time_first[d];
    float alpha = 0.f, beta = 0.f, eps = -1e30f;
    size_t base = (size_t)b * TT * DV + d;
    for (int t = 0; t < TT; ++t) {
        size_t idx = base + (size_t)t * DV;
        float kt = bf2f(k[idx]);
        float vt = bf2f(v[idx]);
        float ukt = u + kt;
        float tau = fmaxf(ukt, eps);
        float e1 = __expf(eps - tau);
        float e2 = __expf(ukt - tau);
        float out = (e1*alpha + e2*vt) / (e1*beta + e2);
        float weps = eps - w;
        float tau2 = fmaxf(weps, kt);
        float d1 = __expf(weps - tau2);
        float d2 = __expf(kt - tau2);
        alpha = d1*alpha + d2*vt;
        beta  = d1*beta + d2;
        eps = tau2;
        float rt = bf2f(r[idx]);
        float sr = 1.f / (1.f + __expf(-rt));
        aout[idx] = f2bf(out * sr);
    }
}

// ---------------- bf16 MFMA GEMM: C[M,N] = A[M,K] @ Bt[N,K]^T, epilogue by MODE ----------------
// MODE 1: C bf16 = acc
// MODE 3: C bf16 = relu(acc)^2
// MODE 5: C bf16 = acc + res_f32
// MODE 6: C f32  = res_bf16 + sigmoid(gate_bf16) * acc
template<int MODE>
__global__ __launch_bounds__(256) void gemm_bf16(
    const short* __restrict__ A, const short* __restrict__ Bt,
    void* __restrict__ Cout, int M, int N, int K,
    const void* __restrict__ res, const unsigned short* __restrict__ gate)
{
    __shared__ short sA[128 * 40];
    __shared__ short sB[128 * 40];
    const int m0 = blockIdx.y * 128, n0 = blockIdx.x * 128;
    const int t = threadIdx.x;
    const int lane = t & 63, wv = t >> 6;
    const int wr = wv >> 1, wc = wv & 1;
    const int lm = lane & 15, lk = (lane >> 4) * 8;
    const int r0 = t >> 2;            // rows 0..63
    const int r1 = r0 + 64;           // rows 64..127
    const int c0 = (t & 3) * 8;       // k-chunk within 32
    f32x4 acc[4][4] = {};

    for (int k0 = 0; k0 < K; k0 += 32) {
        bf16x8 va0 = *(const bf16x8*)(A  + (size_t)(m0 + r0) * K + k0 + c0);
        bf16x8 va1 = *(const bf16x8*)(A  + (size_t)(m0 + r1) * K + k0 + c0);
        bf16x8 vb0 = *(const bf16x8*)(Bt + (size_t)(n0 + r0) * K + k0 + c0);
        bf16x8 vb1 = *(const bf16x8*)(Bt + (size_t)(n0 + r1) * K + k0 + c0);
        __syncthreads();
        *(bf16x8*)&sA[r0 * 40 + c0] = va0;
        *(bf16x8*)&sA[r1 * 40 + c0] = va1;
        *(bf16x8*)&sB[r0 * 40 + c0] = vb0;
        *(bf16x8*)&sB[r1 * 40 + c0] = vb1;
        __syncthreads();
        bf16x8 af[4], bfr[4];
        #pragma unroll
        for (int i = 0; i < 4; ++i)
            af[i] = *(const bf16x8*)&sA[(wr*64 + i*16 + lm) * 40 + lk];
        #pragma unroll
        for (int j = 0; j < 4; ++j)
            bfr[j] = *(const bf16x8*)&sB[(wc*64 + j*16 + lm) * 40 + lk];
        #pragma unroll
        for (int i = 0; i < 4; ++i)
            #pragma unroll
            for (int j = 0; j < 4; ++j)
                acc[i][j] = __builtin_amdgcn_mfma_f32_16x16x32_bf16(af[i], bfr[j], acc[i][j], 0, 0, 0);
    }

    #pragma unroll
    for (int i = 0; i < 4; ++i)
        #pragma unroll
        for (int j = 0; j < 4; ++j)
            #pragma unroll
            for (int rr = 0; rr < 4; ++rr) {
                int gm = m0 + wr*64 + i*16 + (lane >> 4)*4 + rr;
                int gn = n0 + wc*64 + j*16 + lm;
                size_t off = (size_t)gm * N + gn;
                float val = acc[i][j][rr];
                if (MODE == 1) {
                    ((unsigned short*)Cout)[off] = f2bf(val);
                } else if (MODE == 3) {
                    float rl = fmaxf(val, 0.f);
                    ((unsigned short*)Cout)[off] = f2bf(rl * rl);
                } else if (MODE == 5) {
                    ((unsigned short*)Cout)[off] = f2bf(val + ((const float*)res)[off]);
                } else {
                    float g = bf2f(gate[off]);
                    float sg = 1.f / (1.f + __expf(-g));
                    ((float*)Cout)[off] = bf2f(((const unsigned short*)res)[off]) + sg * val;
                }
            }
}

extern "C" void kernel_launch(void* const* d_in, const int* in_sizes, int n_in,
                              void* d_out, int out_size, void* d_ws, size_t ws_size,
                              hipStream_t stream) {
    const float* x          = (const float*)d_in[0];
    const float* ln1_w      = (const float*)d_in[1];
    const float* ln1_b      = (const float*)d_in[2];
    const float* ln2_w      = (const float*)d_in[3];
    const float* ln2_b      = (const float*)d_in[4];
    const float* time_decay = (const float*)d_in[5];
    const float* time_first = (const float*)d_in[6];
    const float* tmk        = (const float*)d_in[7];
    const float* tmv        = (const float*)d_in[8];
    const float* tmr        = (const float*)d_in[9];
    const float* w_key      = (const float*)d_in[10];
    const float* w_value    = (const float*)d_in[11];
    const float* w_recept   = (const float*)d_in[12];
    const float* w_output   = (const float*)d_in[13];
    const float* f_tmk      = (const float*)d_in[14];
    const float* f_tmr      = (const float*)d_in[15];
    const float* f_w_key    = (const float*)d_in[16];
    const float* f_w_recept = (const float*)d_in[17];
    const float* f_w_value  = (const float*)d_in[18];

    char* ws = (char*)d_ws;
    const size_t MB = 1ull << 20;
    if (ws_size < 160 * MB) {
        // expose ws_size through the absmax report instead of failing silently
        diag_kernel<<<1, 1, 0, stream>>>((float*)d_out, (float)ws_size);
        return;
    }

    // weights (bf16, transposed [N][K]) — 26 MiB total
    unsigned short* wkT  = (unsigned short*)(ws + 0*MB);    // [1024][1024]
    unsigned short* wvT  = (unsigned short*)(ws + 2*MB);
    unsigned short* wrT  = (unsigned short*)(ws + 4*MB);
    unsigned short* woT  = (unsigned short*)(ws + 6*MB);
    unsigned short* fwkT = (unsigned short*)(ws + 8*MB);    // [4096][1024]
    unsigned short* fwrT = (unsigned short*)(ws + 16*MB);   // [1024][1024]
    unsigned short* fwvT = (unsigned short*)(ws + 18*MB);   // [1024][4096]
    // four rotating 32-MiB activation slots ([16384][1024] bf16 each)
    unsigned short* S0 = (unsigned short*)(ws + 32*MB);
    unsigned short* S1 = (unsigned short*)(ws + 64*MB);
    unsigned short* S2 = (unsigned short*)(ws + 96*MB);
    unsigned short* S3 = (unsigned short*)(ws + 128*MB);
    // liveness-checked aliases
    unsigned short* xn    = S0;  // attn LN out
    unsigned short* xk    = S1;
    unsigned short* xv    = S2;
    unsigned short* xr    = S3;
    unsigned short* kbuf  = S0;  // xn dead
    unsigned short* vbuf  = S1;  // xk dead
    unsigned short* rbuf  = S2;  // xv dead
    unsigned short* abuf  = S3;  // xr dead
    unsigned short* x1    = S0;  // kbuf dead (bf16 residual)
    unsigned short* xn2   = S1;  // vbuf dead
    unsigned short* fkx   = S2;  // rbuf dead
    unsigned short* frx   = S3;  // abuf dead
    unsigned short* frbuf = S1;  // xn2 dead
    unsigned short* hk    = S3;  // frx dead ([4096][4096] bf16 chunk)

    dim3 tb(32, 8);
    transpose_cast<<<dim3(32, 32),  tb, 0, stream>>>(w_key,      wkT,  1024, 1024);
    transpose_cast<<<dim3(32, 32),  tb, 0, stream>>>(w_value,    wvT,  1024, 1024);
    transpose_cast<<<dim3(32, 32),  tb, 0, stream>>>(w_recept,   wrT,  1024, 1024);
    transpose_cast<<<dim3(32, 32),  tb, 0, stream>>>(w_output,   woT,  1024, 1024);
    transpose_cast<<<dim3(128, 32), tb, 0, stream>>>(f_w_key,    fwkT, 1024, 4096);
    transpose_cast<<<dim3(32, 32),  tb, 0, stream>>>(f_w_recept, fwrT, 1024, 1024);
    transpose_cast<<<dim3(32, 128), tb, 0, stream>>>(f_w_value,  fwvT, 4096, 1024);

    // --- attention sub-block ---
    ln_kernel<false><<<MM, 256, 0, stream>>>(x, ln1_w, ln1_b, xn);
    mix_kernel<<<MM*DV/8/256, 256, 0, stream>>>(xn, tmk, tmv, tmr, xk, xv, xr);
    gemm_bf16<1><<<dim3(8, 128), 256, 0, stream>>>((const short*)xk, (const short*)wkT, kbuf, MM, 1024, 1024, nullptr, nullptr);
    gemm_bf16<1><<<dim3(8, 128), 256, 0, stream>>>((const short*)xv, (const short*)wvT, vbuf, MM, 1024, 1024, nullptr, nullptr);
    gemm_bf16<1><<<dim3(8, 128), 256, 0, stream>>>((const short*)xr, (const short*)wrT, rbuf, MM, 1024, 1024, nullptr, nullptr);
    wkv_kernel<<<16, 256, 0, stream>>>(kbuf, vbuf, rbuf, time_decay, time_first, abuf);
    gemm_bf16<5><<<dim3(8, 128), 256, 0, stream>>>((const short*)abuf, (const short*)woT, x1, MM, 1024, 1024, x, nullptr);

    // --- feed-forward sub-block ---
    ln_kernel<true><<<MM, 256, 0, stream>>>(x1, ln2_w, ln2_b, xn2);
    mix_kernel<<<MM*DV/8/256, 256, 0, stream>>>(xn2, f_tmk, f_tmr, nullptr, fkx, frx, nullptr);
    gemm_bf16<1><<<dim3(8, 128), 256, 0, stream>>>((const short*)frx, (const short*)fwrT, frbuf, MM, 1024, 1024, nullptr, nullptr);
    // fk + final GEMM, M-chunked x4 so hk fits in one 32-MiB slot
    for (int c = 0; c < 4; ++c) {
        const size_t rows = 4096;
        const size_t aoff = (size_t)c * rows * 1024;
        gemm_bf16<3><<<dim3(32, 32), 256, 0, stream>>>(
            (const short*)(fkx + aoff), (const short*)fwkT, hk, rows, 4096, 1024, nullptr, nullptr);
        gemm_bf16<6><<<dim3(8, 32), 256, 0, stream>>>(
            (const short*)hk, (const short*)fwvT, (float*)d_out + aoff, rows, 1024, 4096,
            x1 + aoff, frbuf + aoff);
    }
}

// Round 4
// 1337.937 us; speedup vs baseline: 2.1523x; 2.1523x over previous
//
#include <hip/hip_runtime.h>

#define DV 1024
#define TT 4096
#define BB 4
#define FF 4096
#define MM (BB*TT)   // 16384 rows
#define NCH 64       // WKV chunks
#define LCH 64       // WKV chunk length (NCH*LCH == TT)

typedef __attribute__((ext_vector_type(8))) short bf16x8;
typedef __attribute__((ext_vector_type(4))) float f32x4;
typedef __attribute__((ext_vector_type(8))) unsigned short u16x8;
typedef __attribute__((ext_vector_type(4))) unsigned short u16x4;

__device__ __forceinline__ float bf2f(unsigned short h) {
    union { unsigned int u; float f; } c; c.u = ((unsigned int)h) << 16; return c.f;
}
__device__ __forceinline__ unsigned short f2bf(float f) {
    union { float f; unsigned int u; } c; c.f = f;
    unsigned int r = c.u + 0x7fffu + ((c.u >> 16) & 1u);
    return (unsigned short)(r >> 16);
}

// diag: if workspace too small, expose ws_size via absmax
__global__ void diag_kernel(float* out, float v) { out[0] = v; }

// ---------------- weight cast+transpose: f32 [K][N] -> bf16 [N][K] ----------------
__global__ __launch_bounds__(256) void transpose_cast(
    const float* __restrict__ src, unsigned short* __restrict__ dst, int K, int N)
{
    __shared__ float t[32][33];
    int n0 = blockIdx.x * 32, k0 = blockIdx.y * 32;
    int tx = threadIdx.x, ty = threadIdx.y;  // block (32,8)
    #pragma unroll
    for (int i = 0; i < 4; ++i)
        t[ty*4+i][tx] = src[(size_t)(k0 + ty*4 + i) * N + n0 + tx];
    __syncthreads();
    #pragma unroll
    for (int i = 0; i < 4; ++i)
        dst[(size_t)(n0 + ty*4 + i) * K + k0 + tx] = f2bf(t[tx][ty*4+i]);
}

// ---------------- LayerNorm: (f32|bf16) [rows][1024] -> bf16 ----------------
template<bool BF16IN>
__global__ __launch_bounds__(256) void ln_kernel(
    const void* __restrict__ xin, const float* __restrict__ w, const float* __restrict__ b,
    unsigned short* __restrict__ out)
{
    int row = blockIdx.x;
    int t = threadIdx.x;
    float v0, v1, v2, v3;
    if (BF16IN) {
        u16x4 h = *(const u16x4*)((const unsigned short*)xin + (size_t)row * DV + t * 4);
        v0 = bf2f(h[0]); v1 = bf2f(h[1]); v2 = bf2f(h[2]); v3 = bf2f(h[3]);
    } else {
        float4 v = ((const float4*)((const float*)xin + (size_t)row * DV))[t];
        v0 = v.x; v1 = v.y; v2 = v.z; v3 = v.w;
    }
    float s = v0 + v1 + v2 + v3;
    float q = v0*v0 + v1*v1 + v2*v2 + v3*v3;
    #pragma unroll
    for (int off = 32; off >= 1; off >>= 1) {
        s += __shfl_down(s, off);
        q += __shfl_down(q, off);
    }
    __shared__ float ss[4], qq[4];
    if ((t & 63) == 0) { ss[t >> 6] = s; qq[t >> 6] = q; }
    __syncthreads();
    s = ss[0] + ss[1] + ss[2] + ss[3];
    q = qq[0] + qq[1] + qq[2] + qq[3];
    float mu = s * (1.f/DV);
    float var = q * (1.f/DV) - mu*mu;
    float rs = rsqrtf(var + 1e-5f);
    int d = t * 4;
    u16x4 o;
    o[0] = f2bf((v0 - mu)*rs*w[d+0] + b[d+0]);
    o[1] = f2bf((v1 - mu)*rs*w[d+1] + b[d+1]);
    o[2] = f2bf((v2 - mu)*rs*w[d+2] + b[d+2]);
    o[3] = f2bf((v3 - mu)*rs*w[d+3] + b[d+3]);
    *(u16x4*)(out + (size_t)row*DV + d) = o;
}

// ---------------- time-shift mix: out = xn*c + shift(xn)*(1-c), 2 or 3 outputs ----------------
__global__ __launch_bounds__(256) void mix_kernel(
    const unsigned short* __restrict__ xn,
    const float* __restrict__ ck, const float* __restrict__ cv, const float* __restrict__ cr,
    unsigned short* __restrict__ ok, unsigned short* __restrict__ ov, unsigned short* __restrict__ orr)
{
    int gid = blockIdx.x * 256 + threadIdx.x;   // MM*DV/8 total
    int row = gid >> 7;
    int d0 = (gid & 127) << 3;
    size_t base = (size_t)row * DV + d0;
    u16x8 cur = *(const u16x8*)(xn + base);
    bool hp = (row & (TT - 1)) != 0;
    u16x8 prev = (u16x8)0;
    if (hp) prev = *(const u16x8*)(xn + base - DV);
    u16x8 rk, rv, rr2;
    #pragma unroll
    for (int e = 0; e < 8; ++e) {
        float xc = bf2f(cur[e]);
        float xp = hp ? bf2f(prev[e]) : 0.f;
        float a = ck[d0+e]; rk[e] = f2bf(xc*a + xp*(1.f-a));
        float bb = cv[d0+e]; rv[e] = f2bf(xc*bb + xp*(1.f-bb));
        if (orr) { float c = cr[d0+e]; rr2[e] = f2bf(xc*c + xp*(1.f-c)); }
    }
    *(u16x8*)(ok + base) = rk;
    *(u16x8*)(ov + base) = rv;
    if (orr) *(u16x8*)(orr + base) = rr2;
}

// ---------------- WKV chunk-parallel scan ----------------
// gid = ((b*NCH + c)*DV + d); thread handles chunk c of channel (b,d).

// Phase 1: per-chunk local contribution (alpha, beta, m) with zero init.
__global__ __launch_bounds__(256) void wkv_phase1(
    const unsigned short* __restrict__ k, const unsigned short* __restrict__ v,
    const float* __restrict__ time_decay,
    float* __restrict__ saP, float* __restrict__ sbP, float* __restrict__ mP)
{
    int gid = blockIdx.x * 256 + threadIdx.x;      // 262144
    int d = gid & (DV - 1);
    int bc = gid >> 10;
    int b = bc >> 6, c = bc & (NCH - 1);
    float w = __expf(time_decay[d]);
    float alpha = 0.f, beta = 0.f, m = -1e30f;
    size_t base = ((size_t)b * TT + (size_t)c * LCH) * DV + d;
    for (int t = 0; t < LCH; ++t) {
        size_t idx = base + (size_t)t * DV;
        float kt = bf2f(k[idx]);
        float vt = bf2f(v[idx]);
        float wm = m - w;
        float tau = fmaxf(wm, kt);
        float d1 = __expf(wm - tau);
        float d2 = __expf(kt - tau);
        alpha = d1*alpha + d2*vt;
        beta  = d1*beta + d2;
        m = tau;
    }
    saP[gid] = alpha; sbP[gid] = beta; mP[gid] = m;
}

// Phase 2: sequential scan over chunk summaries per channel; rewrites
// (contrib_c) slots with the INCOMING state of chunk c, in place.
__global__ __launch_bounds__(256) void wkv_phase2(
    const float* __restrict__ time_decay,
    float* __restrict__ saP, float* __restrict__ sbP, float* __restrict__ mP)
{
    int gid = blockIdx.x * 256 + threadIdx.x;      // 4096
    int b = gid >> 10, d = gid & (DV - 1);
    float Lw = (float)LCH * __expf(time_decay[d]);
    float A = 0.f, Bv = 0.f, E = -1e30f;           // incoming state of chunk 0
    for (int c = 0; c < NCH; ++c) {
        int idx = ((b * NCH + c) << 10) + d;
        float sa = saP[idx], sb = sbP[idx], mc = mP[idx];
        saP[idx] = A; sbP[idx] = Bv; mP[idx] = E;  // store incoming state
        // S_{c+1} = e^{-Lw} * S_c + contrib_c   (log-scaled)
        float de = E - Lw;
        float m2 = fmaxf(de, mc);
        float e1 = __expf(de - m2);
        float e2 = __expf(mc - m2);
        A  = e1*A  + e2*sa;
        Bv = e1*Bv + e2*sb;
        E  = m2;
    }
}

// Phase 3: replay reference recurrence per chunk from incoming state; emit
// bf16 out * sigmoid(r).
__global__ __launch_bounds__(256) void wkv_phase3(
    const unsigned short* __restrict__ k, const unsigned short* __restrict__ v,
    const unsigned short* __restrict__ r,
    const float* __restrict__ time_decay, const float* __restrict__ time_first,
    const float* __restrict__ saP, const float* __restrict__ sbP, const float* __restrict__ mP,
    unsigned short* __restrict__ aout)
{
    int gid = blockIdx.x * 256 + threadIdx.x;      // 262144
    int d = gid & (DV - 1);
    int bc = gid >> 10;
    int b = bc >> 6, c = bc & (NCH - 1);
    float w = __expf(time_decay[d]);
    float u = time_first[d];
    float alpha = saP[gid], beta = sbP[gid], eps = mP[gid];
    size_t base = ((size_t)b * TT + (size_t)c * LCH) * DV + d;
    for (int t = 0; t < LCH; ++t) {
        size_t idx = base + (size_t)t * DV;
        float kt = bf2f(k[idx]);
        float vt = bf2f(v[idx]);
        float ukt = u + kt;
        float tau = fmaxf(ukt, eps);
        float e1 = __expf(eps - tau);
        float e2 = __expf(ukt - tau);
        float out = (e1*alpha + e2*vt) / (e1*beta + e2);
        float weps = eps - w;
        float tau2 = fmaxf(weps, kt);
        float d1 = __expf(weps - tau2);
        float d2 = __expf(kt - tau2);
        alpha = d1*alpha + d2*vt;
        beta  = d1*beta + d2;
        eps = tau2;
        float rt = bf2f(r[idx]);
        float sr = 1.f / (1.f + __expf(-rt));
        aout[idx] = f2bf(out * sr);
    }
}

// ---------------- bf16 MFMA GEMM: C[M,N] = A[M,K] @ Bt[N,K]^T, epilogue by MODE ----------------
// MODE 1: C bf16 = acc
// MODE 3: C bf16 = relu(acc)^2
// MODE 5: C bf16 = acc + res_f32
// MODE 6: C f32  = res_bf16 + sigmoid(gate_bf16) * acc
template<int MODE>
__global__ __launch_bounds__(256) void gemm_bf16(
    const short* __restrict__ A, const short* __restrict__ Bt,
    void* __restrict__ Cout, int M, int N, int K,
    const void* __restrict__ res, const unsigned short* __restrict__ gate)
{
    __shared__ short sA[128 * 40];
    __shared__ short sB[128 * 40];
    const int m0 = blockIdx.y * 128, n0 = blockIdx.x * 128;
    const int t = threadIdx.x;
    const int lane = t & 63, wv = t >> 6;
    const int wr = wv >> 1, wc = wv & 1;
    const int lm = lane & 15, lk = (lane >> 4) * 8;
    const int r0 = t >> 2;            // rows 0..63
    const int r1 = r0 + 64;           // rows 64..127
    const int c0 = (t & 3) * 8;       // k-chunk within 32
    f32x4 acc[4][4] = {};

    for (int k0 = 0; k0 < K; k0 += 32) {
        bf16x8 va0 = *(const bf16x8*)(A  + (size_t)(m0 + r0) * K + k0 + c0);
        bf16x8 va1 = *(const bf16x8*)(A  + (size_t)(m0 + r1) * K + k0 + c0);
        bf16x8 vb0 = *(const bf16x8*)(Bt + (size_t)(n0 + r0) * K + k0 + c0);
        bf16x8 vb1 = *(const bf16x8*)(Bt + (size_t)(n0 + r1) * K + k0 + c0);
        __syncthreads();
        *(bf16x8*)&sA[r0 * 40 + c0] = va0;
        *(bf16x8*)&sA[r1 * 40 + c0] = va1;
        *(bf16x8*)&sB[r0 * 40 + c0] = vb0;
        *(bf16x8*)&sB[r1 * 40 + c0] = vb1;
        __syncthreads();
        bf16x8 af[4], bfr[4];
        #pragma unroll
        for (int i = 0; i < 4; ++i)
            af[i] = *(const bf16x8*)&sA[(wr*64 + i*16 + lm) * 40 + lk];
        #pragma unroll
        for (int j = 0; j < 4; ++j)
            bfr[j] = *(const bf16x8*)&sB[(wc*64 + j*16 + lm) * 40 + lk];
        #pragma unroll
        for (int i = 0; i < 4; ++i)
            #pragma unroll
            for (int j = 0; j < 4; ++j)
                acc[i][j] = __builtin_amdgcn_mfma_f32_16x16x32_bf16(af[i], bfr[j], acc[i][j], 0, 0, 0);
    }

    #pragma unroll
    for (int i = 0; i < 4; ++i)
        #pragma unroll
        for (int j = 0; j < 4; ++j)
            #pragma unroll
            for (int rr = 0; rr < 4; ++rr) {
                int gm = m0 + wr*64 + i*16 + (lane >> 4)*4 + rr;
                int gn = n0 + wc*64 + j*16 + lm;
                size_t off = (size_t)gm * N + gn;
                float val = acc[i][j][rr];
                if (MODE == 1) {
                    ((unsigned short*)Cout)[off] = f2bf(val);
                } else if (MODE == 3) {
                    float rl = fmaxf(val, 0.f);
                    ((unsigned short*)Cout)[off] = f2bf(rl * rl);
                } else if (MODE == 5) {
                    ((unsigned short*)Cout)[off] = f2bf(val + ((const float*)res)[off]);
                } else {
                    float g = bf2f(gate[off]);
                    float sg = 1.f / (1.f + __expf(-g));
                    ((float*)Cout)[off] = bf2f(((const unsigned short*)res)[off]) + sg * val;
                }
            }
}

extern "C" void kernel_launch(void* const* d_in, const int* in_sizes, int n_in,
                              void* d_out, int out_size, void* d_ws, size_t ws_size,
                              hipStream_t stream) {
    const float* x          = (const float*)d_in[0];
    const float* ln1_w      = (const float*)d_in[1];
    const float* ln1_b      = (const float*)d_in[2];
    const float* ln2_w      = (const float*)d_in[3];
    const float* ln2_b      = (const float*)d_in[4];
    const float* time_decay = (const float*)d_in[5];
    const float* time_first = (const float*)d_in[6];
    const float* tmk        = (const float*)d_in[7];
    const float* tmv        = (const float*)d_in[8];
    const float* tmr        = (const float*)d_in[9];
    const float* w_key      = (const float*)d_in[10];
    const float* w_value    = (const float*)d_in[11];
    const float* w_recept   = (const float*)d_in[12];
    const float* w_output   = (const float*)d_in[13];
    const float* f_tmk      = (const float*)d_in[14];
    const float* f_tmr      = (const float*)d_in[15];
    const float* f_w_key    = (const float*)d_in[16];
    const float* f_w_recept = (const float*)d_in[17];
    const float* f_w_value  = (const float*)d_in[18];

    char* ws = (char*)d_ws;
    const size_t MB = 1ull << 20;
    if (ws_size < 160 * MB) {
        diag_kernel<<<1, 1, 0, stream>>>((float*)d_out, (float)ws_size);
        return;
    }

    // weights (bf16, transposed [N][K]) — 26 MiB total
    unsigned short* wkT  = (unsigned short*)(ws + 0*MB);    // [1024][1024]
    unsigned short* wvT  = (unsigned short*)(ws + 2*MB);
    unsigned short* wrT  = (unsigned short*)(ws + 4*MB);
    unsigned short* woT  = (unsigned short*)(ws + 6*MB);
    unsigned short* fwkT = (unsigned short*)(ws + 8*MB);    // [4096][1024]
    unsigned short* fwrT = (unsigned short*)(ws + 16*MB);   // [1024][1024]
    unsigned short* fwvT = (unsigned short*)(ws + 18*MB);   // [1024][4096]
    // WKV chunk summaries: 3 planes x 1 MiB in the 26..32 MiB gap
    float* saP = (float*)(ws + 26*MB);
    float* sbP = (float*)(ws + 27*MB);
    float* mP  = (float*)(ws + 28*MB);
    // four rotating 32-MiB activation slots ([16384][1024] bf16 each)
    unsigned short* S0 = (unsigned short*)(ws + 32*MB);
    unsigned short* S1 = (unsigned short*)(ws + 64*MB);
    unsigned short* S2 = (unsigned short*)(ws + 96*MB);
    unsigned short* S3 = (unsigned short*)(ws + 128*MB);
    // liveness-checked aliases
    unsigned short* xn    = S0;  // attn LN out
    unsigned short* xk    = S1;
    unsigned short* xv    = S2;
    unsigned short* xr    = S3;
    unsigned short* kbuf  = S0;  // xn dead
    unsigned short* vbuf  = S1;  // xk dead
    unsigned short* rbuf  = S2;  // xv dead
    unsigned short* abuf  = S3;  // xr dead
    unsigned short* x1    = S0;  // kbuf dead (bf16 residual)
    unsigned short* xn2   = S1;  // vbuf dead
    unsigned short* fkx   = S2;  // rbuf dead
    unsigned short* frx   = S3;  // abuf dead
    unsigned short* frbuf = S1;  // xn2 dead
    unsigned short* hk    = S3;  // frx dead ([4096][4096] bf16 chunk)

    dim3 tb(32, 8);
    transpose_cast<<<dim3(32, 32),  tb, 0, stream>>>(w_key,      wkT,  1024, 1024);
    transpose_cast<<<dim3(32, 32),  tb, 0, stream>>>(w_value,    wvT,  1024, 1024);
    transpose_cast<<<dim3(32, 32),  tb, 0, stream>>>(w_recept,   wrT,  1024, 1024);
    transpose_cast<<<dim3(32, 32),  tb, 0, stream>>>(w_output,   woT,  1024, 1024);
    transpose_cast<<<dim3(128, 32), tb, 0, stream>>>(f_w_key,    fwkT, 1024, 4096);
    transpose_cast<<<dim3(32, 32),  tb, 0, stream>>>(f_w_recept, fwrT, 1024, 1024);
    transpose_cast<<<dim3(32, 128), tb, 0, stream>>>(f_w_value,  fwvT, 4096, 1024);

    // --- attention sub-block ---
    ln_kernel<false><<<MM, 256, 0, stream>>>(x, ln1_w, ln1_b, xn);
    mix_kernel<<<MM*DV/8/256, 256, 0, stream>>>(xn, tmk, tmv, tmr, xk, xv, xr);
    gemm_bf16<1><<<dim3(8, 128), 256, 0, stream>>>((const short*)xk, (const short*)wkT, kbuf, MM, 1024, 1024, nullptr, nullptr);
    gemm_bf16<1><<<dim3(8, 128), 256, 0, stream>>>((const short*)xv, (const short*)wvT, vbuf, MM, 1024, 1024, nullptr, nullptr);
    gemm_bf16<1><<<dim3(8, 128), 256, 0, stream>>>((const short*)xr, (const short*)wrT, rbuf, MM, 1024, 1024, nullptr, nullptr);
    // chunk-parallel WKV
    wkv_phase1<<<BB*NCH*DV/256, 256, 0, stream>>>(kbuf, vbuf, time_decay, saP, sbP, mP);
    wkv_phase2<<<BB*DV/256, 256, 0, stream>>>(time_decay, saP, sbP, mP);
    wkv_phase3<<<BB*NCH*DV/256, 256, 0, stream>>>(kbuf, vbuf, rbuf, time_decay, time_first, saP, sbP, mP, abuf);
    gemm_bf16<5><<<dim3(8, 128), 256, 0, stream>>>((const short*)abuf, (const short*)woT, x1, MM, 1024, 1024, x, nullptr);

    // --- feed-forward sub-block ---
    ln_kernel<true><<<MM, 256, 0, stream>>>(x1, ln2_w, ln2_b, xn2);
    mix_kernel<<<MM*DV/8/256, 256, 0, stream>>>(xn2, f_tmk, f_tmr, nullptr, fkx, frx, nullptr);
    gemm_bf16<1><<<dim3(8, 128), 256, 0, stream>>>((const short*)frx, (const short*)fwrT, frbuf, MM, 1024, 1024, nullptr, nullptr);
    // fk + final GEMM, M-chunked x4 so hk fits in one 32-MiB slot
    for (int c = 0; c < 4; ++c) {
        const size_t rows = 4096;
        const size_t aoff = (size_t)c * rows * 1024;
        gemm_bf16<3><<<dim3(32, 32), 256, 0, stream>>>(
            (const short*)(fkx + aoff), (const short*)fwkT, hk, rows, 4096, 1024, nullptr, nullptr);
        gemm_bf16<6><<<dim3(8, 32), 256, 0, stream>>>(
            (const short*)hk, (const short*)fwvT, (float*)d_out + aoff, rows, 1024, 4096,
            x1 + aoff, frbuf + aoff);
    }
}